// Round 8
// baseline (430.974 us; speedup 1.0000x reference)
//
#include <hip/hip_runtime.h>
#include <math.h>

#define ND 512
#define NK 32

typedef __attribute__((ext_vector_type(8))) short short8;
typedef __attribute__((ext_vector_type(4))) float f32x4;
typedef __attribute__((address_space(1))) const unsigned int glds_src;
typedef __attribute__((address_space(3))) unsigned int glds_dst;

__device__ inline unsigned short f2bf(float x) {
  unsigned u = __float_as_uint(x);
  unsigned r = (u + 0x7fffu + ((u >> 16) & 1u)) >> 16;  // RNE
  return (unsigned short)r;
}
__device__ inline float bf2f(unsigned short h) {
  return __uint_as_float(((unsigned)h) << 16);
}
__device__ inline void gload_lds16(const void* g, void* l) {
  __builtin_amdgcn_global_load_lds((glds_src*)g, (glds_dst*)l, 16, 0, 0);
}
__device__ inline float fast_tanh(float v) {
  const float c = fminf(fmaxf(v, -15.f), 15.f);
  const float e = __expf(2.f * c);
  return 1.f - 2.f / (e + 1.f);
}

// bijective XCD chunking (m204)
__device__ inline int xcd_swz(int orig, int nwg) {
  const int q = nwg >> 3, r = nwg & 7;
  const int xcd = orig & 7, pos = orig >> 3;
  return (xcd < r ? xcd * (q + 1) : r * (q + 1) + (xcd - r) * q) + pos;
}

// ---------------- mask dtype detection ----------------
__global__ void detect_mask_kernel(const unsigned int* __restrict__ m, int nwords,
                                   int* __restrict__ flag) {
  int local = 0;
  for (int i = blockIdx.x * blockDim.x + threadIdx.x; i < nwords;
       i += gridDim.x * blockDim.x) {
    if (m[i] > 1u) local = 1;
  }
  if (__any(local)) {
    if ((threadIdx.x & 63) == 0) atomicOr(flag, 1);
  }
}

// ---------------- fused panel converter (prev + W1 + Wa) ----------------
// per k-block (128 B): 4 groups of [hi 16B | lo 16B], XOR-swizzle ((row&7)<<4).
__device__ inline void conv_chunk(const float* __restrict__ src,
                                  unsigned char* __restrict__ dst,
                                  int rows_src, int Kd, long long c) {
  const int cpr = Kd * 4;
  const int r = (int)(c / cpr);
  const int rem = (int)(c % cpr);
  const int kb = rem >> 2;
  const int s = rem & 3;
  const int sw = (r & 7) << 4;
  unsigned short h[8], l[8];
  if (r < rows_src) {
    const float* p = src + (size_t)r * (Kd * 32) + kb * 32 + s * 8;
    #pragma unroll
    for (int j = 0; j < 8; j++) {
      const float v = p[j];
      h[j] = f2bf(v);
      l[j] = f2bf(v - bf2f(h[j]));
    }
  } else {
    #pragma unroll
    for (int j = 0; j < 8; j++) { h[j] = 0; l[j] = 0; }
  }
  uint4 hv, lv;
  hv.x = (unsigned)h[0] | ((unsigned)h[1] << 16);
  hv.y = (unsigned)h[2] | ((unsigned)h[3] << 16);
  hv.z = (unsigned)h[4] | ((unsigned)h[5] << 16);
  hv.w = (unsigned)h[6] | ((unsigned)h[7] << 16);
  lv.x = (unsigned)l[0] | ((unsigned)l[1] << 16);
  lv.y = (unsigned)l[2] | ((unsigned)l[3] << 16);
  lv.z = (unsigned)l[4] | ((unsigned)l[5] << 16);
  lv.w = (unsigned)l[6] | ((unsigned)l[7] << 16);
  unsigned char* rowb = dst + (size_t)r * (Kd * 128) + kb * 128;
  *(uint4*)(rowb + ((s * 32) ^ sw)) = hv;
  *(uint4*)(rowb + ((s * 32 + 16) ^ sw)) = lv;
}

__global__ void convert_panels3(const float* __restrict__ prev, unsigned char* __restrict__ prevP,
                                int Np, int Mp,
                                const float* __restrict__ W1, unsigned char* __restrict__ W1P,
                                const float* __restrict__ Wa, unsigned char* __restrict__ WaP) {
  const long long c0 = (long long)Mp * 64;          // prev chunks (Kd=16)
  const long long c1 = c0 + 512 * 64;               // + W1 chunks (Kd=16)
  const long long c2 = c1 + 512 * 128;              // + Wa chunks (Kd=32)
  for (long long c = (long long)blockIdx.x * blockDim.x + threadIdx.x; c < c2;
       c += (long long)gridDim.x * blockDim.x) {
    if (c < c0)      conv_chunk(prev, prevP, Np, 16, c);
    else if (c < c1) conv_chunk(W1, W1P, 512, 16, c - c0);
    else             conv_chunk(Wa, WaP, 512, 32, c - c1);
  }
}

// ---------------- gemm1: split-3, single-buffer (proven m97-structure) ---
__global__ __launch_bounds__(256, 3) void gemm_x(
    const unsigned char* __restrict__ A1, const unsigned char* __restrict__ B,
    float* __restrict__ C, int M, int N, int KB)
{
  __shared__ unsigned char AsP[16384];
  __shared__ unsigned char BsP[16384];
  const int tid = threadIdx.x;
  const int lane = tid & 63;
  const int wv = tid >> 6;
  const int wr = wv >> 1, wc = wv & 1;
  const int wgid = xcd_swz(blockIdx.x, gridDim.x);
  const int bm = (wgid >> 2) * 128, bn = (wgid & 3) * 128;

  f32x4 acc[4][4];
  #pragma unroll
  for (int i = 0; i < 4; i++)
    #pragma unroll
    for (int j = 0; j < 4; j++) acc[i][j] = (f32x4){0.f, 0.f, 0.f, 0.f};

  const int s16 = (lane >> 4) * 32;
  const int lrow0 = (wv << 3) + (lane >> 3);
  const int lbyte = (lane & 7) * 16;

  for (int kb = 0; kb < KB; kb++) {
    #pragma unroll
    for (int i = 0; i < 4; i++) {
      const int lrow = i * 32 + lrow0;
      gload_lds16(A1 + (size_t)(bm + lrow) * ((size_t)KB * 128) + (size_t)kb * 128 + lbyte,
                  AsP + i * 4096 + wv * 1024);
      gload_lds16(B + (size_t)(bn + lrow) * ((size_t)KB * 128) + (size_t)kb * 128 + lbyte,
                  BsP + i * 4096 + wv * 1024);
    }
    __syncthreads();

    short8 bh[4], bl[4];
    #pragma unroll
    for (int fn = 0; fn < 4; fn++) {
      const int row = wc * 64 + fn * 16 + (lane & 15);
      const int sw = (row & 7) << 4;
      bh[fn] = *(const short8*)(BsP + row * 128 + (s16 ^ sw));
      bl[fn] = *(const short8*)(BsP + row * 128 + ((s16 + 16) ^ sw));
    }
    #pragma unroll
    for (int fm = 0; fm < 4; fm++) {
      const int row = wr * 64 + fm * 16 + (lane & 15);
      const int sw = (row & 7) << 4;
      const short8 ah = *(const short8*)(AsP + row * 128 + (s16 ^ sw));
      const short8 al = *(const short8*)(AsP + row * 128 + ((s16 + 16) ^ sw));
      #pragma unroll
      for (int fn = 0; fn < 4; fn++) {
        acc[fm][fn] = __builtin_amdgcn_mfma_f32_16x16x32_bf16(ah, bh[fn], acc[fm][fn], 0, 0, 0);
        acc[fm][fn] = __builtin_amdgcn_mfma_f32_16x16x32_bf16(ah, bl[fn], acc[fm][fn], 0, 0, 0);
        acc[fm][fn] = __builtin_amdgcn_mfma_f32_16x16x32_bf16(al, bh[fn], acc[fm][fn], 0, 0, 0);
      }
    }
    __syncthreads();
  }

  #pragma unroll
  for (int fm = 0; fm < 4; fm++) {
    #pragma unroll
    for (int fn = 0; fn < 4; fn++) {
      const int col = bn + wc * 64 + fn * 16 + (lane & 15);
      #pragma unroll
      for (int j = 0; j < 4; j++) {
        const int row = bm + wr * 64 + fm * 16 + (lane >> 4) * 4 + j;
        if (row < M) C[(size_t)row * N + col] = acc[fm][fn][j];
      }
    }
  }
}

// ---------------- gemm2: split-2, counted-vmcnt double-buffer -----------
// Per iter: stage(kb+1)->buf^1; s_waitcnt vmcnt(8) [vmcnt(0) last iter];
// s_barrier (publishes ALL waves' tile-kb loads); ds_read+MFMA buf;
// s_barrier (read-before-overwrite). Tile kb+1's HBM latency flies across
// compute(kb). LDS 64 KB -> 2 blocks/CU (the experiment's cost).
__global__ __launch_bounds__(256, 2) void gemm_out_db(
    const unsigned char* __restrict__ A1,   // aggP  (K-blocks 0..15)
    const unsigned char* __restrict__ A2,   // prevP (K-blocks 16..31)
    const unsigned char* __restrict__ B,    // WaP [512, 4096]
    float* __restrict__ C, int M, int N, int KB)  // KB=32
{
  __shared__ unsigned char AsP[2][16384];
  __shared__ unsigned char BsP[2][16384];
  const int tid = threadIdx.x;
  const int lane = tid & 63;
  const int wv = tid >> 6;
  const int wr = wv >> 1, wc = wv & 1;
  const int wgid = xcd_swz(blockIdx.x, gridDim.x);
  const int bm = (wgid >> 2) * 128, bn = (wgid & 3) * 128;
  const size_t brstride = (size_t)KB * 128;

  f32x4 acc[4][4];
  #pragma unroll
  for (int i = 0; i < 4; i++)
    #pragma unroll
    for (int j = 0; j < 4; j++) acc[i][j] = (f32x4){0.f, 0.f, 0.f, 0.f};

  const int s16 = (lane >> 4) * 32;
  const int lrow0 = (wv << 3) + (lane >> 3);
  const int lbyte = (lane & 7) * 16;

  auto stage = [&](int kbx, int buf) {
    const unsigned char* Ab = (kbx < 16) ? A1 : A2;
    const int akb = kbx & 15;
    #pragma unroll
    for (int i = 0; i < 4; i++) {
      const int lrow = i * 32 + lrow0;
      gload_lds16(Ab + (size_t)(bm + lrow) * 2048 + (size_t)akb * 128 + lbyte,
                  AsP[buf] + i * 4096 + wv * 1024);
      gload_lds16(B + (size_t)(bn + lrow) * brstride + (size_t)kbx * 128 + lbyte,
                  BsP[buf] + i * 4096 + wv * 1024);
    }
  };

  stage(0, 0);  // 8 loads in flight

  for (int kb = 0; kb < KB; kb++) {
    const int cur = kb & 1;
    if (kb + 1 < KB) {
      stage(kb + 1, cur ^ 1);                           // +8 -> 16 in flight
      asm volatile("s_waitcnt vmcnt(8)" ::: "memory");  // tile kb's 8 done
    } else {
      asm volatile("s_waitcnt vmcnt(0)" ::: "memory");  // drain final tile
    }
    __builtin_amdgcn_s_barrier();   // all waves' tile-kb loads published

    const unsigned char* Ac = AsP[cur];
    const unsigned char* Bc = BsP[cur];
    short8 bh[4], bl[4];
    #pragma unroll
    for (int fn = 0; fn < 4; fn++) {
      const int row = wc * 64 + fn * 16 + (lane & 15);
      const int sw = (row & 7) << 4;
      bh[fn] = *(const short8*)(Bc + row * 128 + (s16 ^ sw));
      bl[fn] = *(const short8*)(Bc + row * 128 + ((s16 + 16) ^ sw));
    }
    __builtin_amdgcn_s_setprio(1);
    #pragma unroll
    for (int fm = 0; fm < 4; fm++) {
      const int row = wr * 64 + fm * 16 + (lane & 15);
      const int sw = (row & 7) << 4;
      const short8 ah = *(const short8*)(Ac + row * 128 + (s16 ^ sw));
      #pragma unroll
      for (int fn = 0; fn < 4; fn++) {
        acc[fm][fn] = __builtin_amdgcn_mfma_f32_16x16x32_bf16(ah, bh[fn], acc[fm][fn], 0, 0, 0);
        acc[fm][fn] = __builtin_amdgcn_mfma_f32_16x16x32_bf16(ah, bl[fn], acc[fm][fn], 0, 0, 0);
      }
    }
    __builtin_amdgcn_s_setprio(0);
    __builtin_amdgcn_s_barrier();   // all waves done reading buf[cur]
  }

  #pragma unroll
  for (int fm = 0; fm < 4; fm++) {
    #pragma unroll
    for (int fn = 0; fn < 4; fn++) {
      const int col = bn + wc * 64 + fn * 16 + (lane & 15);
      #pragma unroll
      for (int j = 0; j < 4; j++) {
        const int row = bm + wr * 64 + fm * 16 + (lane >> 4) * 4 + j;
        if (row < M) C[(size_t)row * N + col] = fast_tanh(acc[fm][fn][j]);
      }
    }
  }
}

// ---------------- fused scores + softmax + aggregate ----------------
// One block (512 thr / 8 waves) per row; neigh streamed once through regs.
// x loaded per-lane directly from global (L2 broadcast) — no LDS stage,
// no entry barrier. Output written as panel image for gemm2.
__global__ __launch_bounds__(512) void attn_fused(
    const float* __restrict__ neigh,   // [N, 32, 512]
    const float* __restrict__ x,       // [N, 512] f32
    const void* __restrict__ mask,     // [N, 32] int32 or u8 (see flag)
    const int* __restrict__ mask_is_u8,
    unsigned char* __restrict__ aggP)  // panel image, 2048 B/row
{
  __shared__ float part[8][ND];
  __shared__ float sc_s[NK];
  __shared__ float attn_s[NK];
  __shared__ unsigned char img[2048];
  const int n = blockIdx.x;
  const int tid = threadIdx.x;
  const int wv = tid >> 6;
  const int lane = tid & 63;

  // each lane needs only its own 8 x values — direct global loads
  const float4 xa = *(const float4*)(x + (size_t)n * ND + lane * 4);
  const float4 xb = *(const float4*)(x + (size_t)n * ND + 256 + lane * 4);

  const float4* nbase = (const float4*)(neigh + ((size_t)n * NK + wv * 4) * ND);
  float4 na[4], nb[4];
  #pragma unroll
  for (int j = 0; j < 4; j++) {
    na[j] = nbase[j * 128 + lane];
    nb[j] = nbase[j * 128 + 64 + lane];
  }

  #pragma unroll
  for (int j = 0; j < 4; j++) {
    float p = na[j].x * xa.x + na[j].y * xa.y + na[j].z * xa.z + na[j].w * xa.w
            + nb[j].x * xb.x + nb[j].y * xb.y + nb[j].z * xb.z + nb[j].w * xb.w;
    #pragma unroll
    for (int off = 32; off; off >>= 1) p += __shfl_xor(p, off);
    if (lane == 0) sc_s[wv * 4 + j] = p;
  }
  __syncthreads();

  if (tid < NK) {
    const int mk = (*mask_is_u8)
        ? (int)((const unsigned char*)mask)[(size_t)n * NK + tid]
        : ((const int*)mask)[(size_t)n * NK + tid];
    float s = mk ? -3.4e38f : sc_s[tid];
    float m = s;
    #pragma unroll
    for (int off = 16; off; off >>= 1) m = fmaxf(m, __shfl_xor(m, off, 32));
    const float p = mk ? 0.f : expf(s - m);
    float t = p;
    #pragma unroll
    for (int off = 16; off; off >>= 1) t += __shfl_xor(t, off, 32);
    attn_s[tid] = p / t;
  }
  __syncthreads();

  float4 acc0 = make_float4(0.f, 0.f, 0.f, 0.f);
  float4 acc1 = make_float4(0.f, 0.f, 0.f, 0.f);
  #pragma unroll
  for (int j = 0; j < 4; j++) {
    const float w = attn_s[wv * 4 + j];
    acc0.x = fmaf(w, na[j].x, acc0.x);
    acc0.y = fmaf(w, na[j].y, acc0.y);
    acc0.z = fmaf(w, na[j].z, acc0.z);
    acc0.w = fmaf(w, na[j].w, acc0.w);
    acc1.x = fmaf(w, nb[j].x, acc1.x);
    acc1.y = fmaf(w, nb[j].y, acc1.y);
    acc1.z = fmaf(w, nb[j].z, acc1.z);
    acc1.w = fmaf(w, nb[j].w, acc1.w);
  }
  *(float4*)&part[wv][lane * 4] = acc0;
  *(float4*)&part[wv][256 + lane * 4] = acc1;
  __syncthreads();
  float ssum = 0.f;
  #pragma unroll
  for (int w = 0; w < 8; w++) ssum += part[w][tid];

  // encode into panel-image row (k = tid)
  {
    const int sw = (n & 7) << 4;
    const int kb = tid >> 5;
    const int bu = ((tid >> 3) & 3) * 32 + (tid & 7) * 2;   // bit4 == 0
    const unsigned short h = f2bf(ssum);
    const unsigned short l = f2bf(ssum - bf2f(h));
    *(unsigned short*)(img + kb * 128 + (bu ^ sw)) = h;
    *(unsigned short*)(img + kb * 128 + ((bu | 16) ^ sw)) = l;
  }
  __syncthreads();
  if (tid < 128) {
    *(uint4*)(aggP + (size_t)n * 2048 + tid * 16) = *(const uint4*)(img + tid * 16);
  }
}

extern "C" void kernel_launch(void* const* d_in, const int* in_sizes, int n_in,
                              void* d_out, int out_size, void* d_ws, size_t ws_size,
                              hipStream_t stream) {
  const float* prev  = (const float*)d_in[0];   // [N, 512]
  const float* neigh = (const float*)d_in[1];   // [N, 32, 512]
  const void*  mask  = d_in[2];                 // [N, 32]
  const float* W1    = (const float*)d_in[3];   // [512, 512]
  const float* Wa    = (const float*)d_in[4];   // [512, 1024]
  float* out = (float*)d_out;
  const int N = in_sizes[0] / ND;               // 20000
  const int Mp = ((N + 127) / 128) * 128;       // 20096

  unsigned char* ws = (unsigned char*)d_ws;
  float*         x     = (float*)ws;                         // N*2048 B
  unsigned char* prevP = ws + (size_t)N * 2048;              // Mp*2048
  unsigned char* aggP  = prevP + (size_t)Mp * 2048;          // Mp*2048
  unsigned char* W1P   = aggP + (size_t)Mp * 2048;           // 512*2048
  unsigned char* WaP   = W1P + (size_t)512 * 2048;           // 512*4096
  int*           flag  = (int*)(WaP + (size_t)512 * 4096);

  hipMemsetAsync(flag, 0, sizeof(int), stream);
  detect_mask_kernel<<<64, 256, 0, stream>>>((const unsigned int*)mask,
                                             (N * NK) / 4, flag);

  // pre-encode panel images (single launch)
  convert_panels3<<<2048, 256, 0, stream>>>(prev, prevP, N, Mp, W1, W1P, Wa, WaP);

  const int nwg = (Mp / 128) * 4;  // 1-D grid, bn innermost, XCD-swizzled

  // x = prev @ W1^T  (split-3: score path needs full precision)
  gemm_x<<<nwg, 256, 0, stream>>>(prevP, W1P, x, N, ND, 16);

  // scores -> softmax -> agg (neigh streamed once; agg emitted as panel image)
  attn_fused<<<N, 512, 0, stream>>>(neigh, x, mask, flag, aggP);

  // out = tanh(concat(agg, prev) @ Wa^T)  (split-2, counted-vmcnt dbuf)
  gemm_out_db<<<nwg, 256, 0, stream>>>(aggP, prevP, WaP, out, N, ND, 32);
}

// Round 9
// 352.688 us; speedup vs baseline: 1.2220x; 1.2220x over previous
//
#include <hip/hip_runtime.h>
#include <math.h>

#define ND 512
#define NK 32

typedef __attribute__((ext_vector_type(8))) short short8;
typedef __attribute__((ext_vector_type(4))) float f32x4;
typedef __attribute__((address_space(1))) const unsigned int glds_src;
typedef __attribute__((address_space(3))) unsigned int glds_dst;

__device__ inline unsigned short f2bf(float x) {
  unsigned u = __float_as_uint(x);
  unsigned r = (u + 0x7fffu + ((u >> 16) & 1u)) >> 16;  // RNE
  return (unsigned short)r;
}
__device__ inline float bf2f(unsigned short h) {
  return __uint_as_float(((unsigned)h) << 16);
}
__device__ inline void gload_lds16(const void* g, void* l) {
  __builtin_amdgcn_global_load_lds((glds_src*)g, (glds_dst*)l, 16, 0, 0);
}
__device__ inline float fast_tanh(float v) {
  const float c = fminf(fmaxf(v, -15.f), 15.f);
  const float e = __expf(2.f * c);
  return 1.f - 2.f / (e + 1.f);
}

// bijective XCD chunking (m204)
__device__ inline int xcd_swz(int orig, int nwg) {
  const int q = nwg >> 3, r = nwg & 7;
  const int xcd = orig & 7, pos = orig >> 3;
  return (xcd < r ? xcd * (q + 1) : r * (q + 1) + (xcd - r) * q) + pos;
}

// ---------------- mask dtype detection ----------------
__global__ void detect_mask_kernel(const unsigned int* __restrict__ m, int nwords,
                                   int* __restrict__ flag) {
  int local = 0;
  for (int i = blockIdx.x * blockDim.x + threadIdx.x; i < nwords;
       i += gridDim.x * blockDim.x) {
    if (m[i] > 1u) local = 1;
  }
  if (__any(local)) {
    if ((threadIdx.x & 63) == 0) atomicOr(flag, 1);
  }
}

// ---------------- fused panel converter (prev + W1 + Wa) ----------------
// per k-block (128 B): 4 groups of [hi 16B | lo 16B], XOR-swizzle ((row&7)<<4).
__device__ inline void conv_chunk(const float* __restrict__ src,
                                  unsigned char* __restrict__ dst,
                                  int rows_src, int Kd, long long c) {
  const int cpr = Kd * 4;
  const int r = (int)(c / cpr);
  const int rem = (int)(c % cpr);
  const int kb = rem >> 2;
  const int s = rem & 3;
  const int sw = (r & 7) << 4;
  unsigned short h[8], l[8];
  if (r < rows_src) {
    const float* p = src + (size_t)r * (Kd * 32) + kb * 32 + s * 8;
    #pragma unroll
    for (int j = 0; j < 8; j++) {
      const float v = p[j];
      h[j] = f2bf(v);
      l[j] = f2bf(v - bf2f(h[j]));
    }
  } else {
    #pragma unroll
    for (int j = 0; j < 8; j++) { h[j] = 0; l[j] = 0; }
  }
  uint4 hv, lv;
  hv.x = (unsigned)h[0] | ((unsigned)h[1] << 16);
  hv.y = (unsigned)h[2] | ((unsigned)h[3] << 16);
  hv.z = (unsigned)h[4] | ((unsigned)h[5] << 16);
  hv.w = (unsigned)h[6] | ((unsigned)h[7] << 16);
  lv.x = (unsigned)l[0] | ((unsigned)l[1] << 16);
  lv.y = (unsigned)l[2] | ((unsigned)l[3] << 16);
  lv.z = (unsigned)l[4] | ((unsigned)l[5] << 16);
  lv.w = (unsigned)l[6] | ((unsigned)l[7] << 16);
  unsigned char* rowb = dst + (size_t)r * (Kd * 128) + kb * 128;
  *(uint4*)(rowb + ((s * 32) ^ sw)) = hv;
  *(uint4*)(rowb + ((s * 32 + 16) ^ sw)) = lv;
}

__global__ void convert_panels3(const float* __restrict__ prev, unsigned char* __restrict__ prevP,
                                int Np, int Mp,
                                const float* __restrict__ W1, unsigned char* __restrict__ W1P,
                                const float* __restrict__ Wa, unsigned char* __restrict__ WaP) {
  const long long c0 = (long long)Mp * 64;          // prev chunks (Kd=16)
  const long long c1 = c0 + 512 * 64;               // + W1 chunks (Kd=16)
  const long long c2 = c1 + 512 * 128;              // + Wa chunks (Kd=32)
  for (long long c = (long long)blockIdx.x * blockDim.x + threadIdx.x; c < c2;
       c += (long long)gridDim.x * blockDim.x) {
    if (c < c0)      conv_chunk(prev, prevP, Np, 16, c);
    else if (c < c1) conv_chunk(W1, W1P, 512, 16, c - c0);
    else             conv_chunk(Wa, WaP, 512, 32, c - c1);
  }
}

// ---------------- split-bf16 MFMA GEMM on panel images ----------------
// Single-buffered m97 structure (proven best here; dbuf variants cost
// occupancy — R4/R8). 128x128 tile, BK=32, 256 thr / 4 waves, 4x4 frags
// 16x16x32. LH ? 3 MFMA (hh+hl+lh ~ f32) : 2 MFMA (hh+hl, tanh-output path).
template<bool SPLIT, bool TANH, bool LH>
__global__ __launch_bounds__(256, 3) void gemm_mfma(
    const unsigned char* __restrict__ A1, const unsigned char* __restrict__ A2,
    const unsigned char* __restrict__ B, float* __restrict__ C,
    int M, int N, int KB)
{
  __shared__ unsigned char AsP[16384];
  __shared__ unsigned char BsP[16384];
  const int tid = threadIdx.x;
  const int lane = tid & 63;
  const int wv = tid >> 6;
  const int wr = wv >> 1, wc = wv & 1;
  const int wgid = xcd_swz(blockIdx.x, gridDim.x);
  const int bm = (wgid >> 2) * 128, bn = (wgid & 3) * 128;
  const size_t brstride = (size_t)KB * 128;
  const size_t arstride = SPLIT ? 2048 : (size_t)KB * 128;

  f32x4 acc[4][4];
  #pragma unroll
  for (int i = 0; i < 4; i++)
    #pragma unroll
    for (int j = 0; j < 4; j++) acc[i][j] = (f32x4){0.f, 0.f, 0.f, 0.f};

  const int s16 = (lane >> 4) * 32;
  const int lrow0 = (wv << 3) + (lane >> 3);
  const int lbyte = (lane & 7) * 16;

  for (int kb = 0; kb < KB; kb++) {
    const unsigned char* Ab;
    int akb;
    if (SPLIT) { Ab = (kb < 16) ? A1 : A2; akb = kb & 15; }
    else       { Ab = A1; akb = kb; }
    #pragma unroll
    for (int i = 0; i < 4; i++) {
      const int lrow = i * 32 + lrow0;
      gload_lds16(Ab + (size_t)(bm + lrow) * arstride + (size_t)akb * 128 + lbyte,
                  AsP + i * 4096 + wv * 1024);
      gload_lds16(B + (size_t)(bn + lrow) * brstride + (size_t)kb * 128 + lbyte,
                  BsP + i * 4096 + wv * 1024);
    }
    __syncthreads();

    short8 bh[4], bl[4];
    #pragma unroll
    for (int fn = 0; fn < 4; fn++) {
      const int row = wc * 64 + fn * 16 + (lane & 15);
      const int sw = (row & 7) << 4;
      bh[fn] = *(const short8*)(BsP + row * 128 + (s16 ^ sw));
      bl[fn] = *(const short8*)(BsP + row * 128 + ((s16 + 16) ^ sw));
    }
    #pragma unroll
    for (int fm = 0; fm < 4; fm++) {
      const int row = wr * 64 + fm * 16 + (lane & 15);
      const int sw = (row & 7) << 4;
      const short8 ah = *(const short8*)(AsP + row * 128 + (s16 ^ sw));
      short8 al;
      if (LH) al = *(const short8*)(AsP + row * 128 + ((s16 + 16) ^ sw));
      #pragma unroll
      for (int fn = 0; fn < 4; fn++) {
        acc[fm][fn] = __builtin_amdgcn_mfma_f32_16x16x32_bf16(ah, bh[fn], acc[fm][fn], 0, 0, 0);
        acc[fm][fn] = __builtin_amdgcn_mfma_f32_16x16x32_bf16(ah, bl[fn], acc[fm][fn], 0, 0, 0);
        if (LH)
          acc[fm][fn] = __builtin_amdgcn_mfma_f32_16x16x32_bf16(al, bh[fn], acc[fm][fn], 0, 0, 0);
      }
    }
    __syncthreads();
  }

  #pragma unroll
  for (int fm = 0; fm < 4; fm++) {
    #pragma unroll
    for (int fn = 0; fn < 4; fn++) {
      const int col = bn + wc * 64 + fn * 16 + (lane & 15);
      #pragma unroll
      for (int j = 0; j < 4; j++) {
        const int row = bm + wr * 64 + fm * 16 + (lane >> 4) * 4 + j;
        if (row < M) {
          float v = acc[fm][fn][j];
          if (TANH) v = fast_tanh(v);
          C[(size_t)row * N + col] = v;
        }
      }
    }
  }
}

// ---------------- fused scores + softmax + aggregate ----------------
// One block (512 thr / 8 waves) per row; UNMASKED neighbors streamed once
// (masked rows never loaded — wave-uniform skip, ~19% HBM cut). x loaded
// per-lane directly (L2 broadcast). Output written as panel image.
__global__ __launch_bounds__(512) void attn_fused(
    const float* __restrict__ neigh,   // [N, 32, 512]
    const float* __restrict__ x,       // [N, 512] f32
    const void* __restrict__ mask,     // [N, 32] int32 or u8 (see flag)
    const int* __restrict__ mask_is_u8,
    unsigned char* __restrict__ aggP)  // panel image, 2048 B/row
{
  __shared__ float part[8][ND];
  __shared__ float sc_s[NK];
  __shared__ float attn_s[NK];
  __shared__ unsigned char img[2048];
  const int n = blockIdx.x;
  const int tid = threadIdx.x;
  const int wv = tid >> 6;
  const int lane = tid & 63;

  // wave-uniform mask for this wave's 4 neighbors (same-addr load = broadcast)
  const int u8m = *mask_is_u8;
  int mk[4];
  #pragma unroll
  for (int j = 0; j < 4; j++) {
    mk[j] = u8m ? (int)((const unsigned char*)mask)[(size_t)n * NK + wv * 4 + j]
                : ((const int*)mask)[(size_t)n * NK + wv * 4 + j];
  }

  // each lane needs only its own 8 x values — direct global loads
  const float4 xa = *(const float4*)(x + (size_t)n * ND + lane * 4);
  const float4 xb = *(const float4*)(x + (size_t)n * ND + 256 + lane * 4);

  const float4* nbase = (const float4*)(neigh + ((size_t)n * NK + wv * 4) * ND);
  float4 na[4], nb[4];

  // scores: load + dot only for unmasked neighbors (wave-uniform branch)
  #pragma unroll
  for (int j = 0; j < 4; j++) {
    if (!mk[j]) {
      na[j] = nbase[j * 128 + lane];
      nb[j] = nbase[j * 128 + 64 + lane];
      float p = na[j].x * xa.x + na[j].y * xa.y + na[j].z * xa.z + na[j].w * xa.w
              + nb[j].x * xb.x + nb[j].y * xb.y + nb[j].z * xb.z + nb[j].w * xb.w;
      #pragma unroll
      for (int off = 32; off; off >>= 1) p += __shfl_xor(p, off);
      if (lane == 0) sc_s[wv * 4 + j] = p;
    }
  }
  __syncthreads();

  if (tid < NK) {
    const int mks = u8m
        ? (int)((const unsigned char*)mask)[(size_t)n * NK + tid]
        : ((const int*)mask)[(size_t)n * NK + tid];
    float s = mks ? -3.4e38f : sc_s[tid];
    float m = s;
    #pragma unroll
    for (int off = 16; off; off >>= 1) m = fmaxf(m, __shfl_xor(m, off, 32));
    const float p = mks ? 0.f : expf(s - m);
    float t = p;
    #pragma unroll
    for (int off = 16; off; off >>= 1) t += __shfl_xor(t, off, 32);
    attn_s[tid] = p / t;
  }
  __syncthreads();

  float4 acc0 = make_float4(0.f, 0.f, 0.f, 0.f);
  float4 acc1 = make_float4(0.f, 0.f, 0.f, 0.f);
  #pragma unroll
  for (int j = 0; j < 4; j++) {
    if (!mk[j]) {
      const float w = attn_s[wv * 4 + j];
      acc0.x = fmaf(w, na[j].x, acc0.x);
      acc0.y = fmaf(w, na[j].y, acc0.y);
      acc0.z = fmaf(w, na[j].z, acc0.z);
      acc0.w = fmaf(w, na[j].w, acc0.w);
      acc1.x = fmaf(w, nb[j].x, acc1.x);
      acc1.y = fmaf(w, nb[j].y, acc1.y);
      acc1.z = fmaf(w, nb[j].z, acc1.z);
      acc1.w = fmaf(w, nb[j].w, acc1.w);
    }
  }
  *(float4*)&part[wv][lane * 4] = acc0;
  *(float4*)&part[wv][256 + lane * 4] = acc1;
  __syncthreads();
  float ssum = 0.f;
  #pragma unroll
  for (int w = 0; w < 8; w++) ssum += part[w][tid];

  // encode into panel-image row (k = tid)
  {
    const int sw = (n & 7) << 4;
    const int kb = tid >> 5;
    const int bu = ((tid >> 3) & 3) * 32 + (tid & 7) * 2;   // bit4 == 0
    const unsigned short h = f2bf(ssum);
    const unsigned short l = f2bf(ssum - bf2f(h));
    *(unsigned short*)(img + kb * 128 + (bu ^ sw)) = h;
    *(unsigned short*)(img + kb * 128 + ((bu | 16) ^ sw)) = l;
  }
  __syncthreads();
  if (tid < 128) {
    *(uint4*)(aggP + (size_t)n * 2048 + tid * 16) = *(const uint4*)(img + tid * 16);
  }
}

extern "C" void kernel_launch(void* const* d_in, const int* in_sizes, int n_in,
                              void* d_out, int out_size, void* d_ws, size_t ws_size,
                              hipStream_t stream) {
  const float* prev  = (const float*)d_in[0];   // [N, 512]
  const float* neigh = (const float*)d_in[1];   // [N, 32, 512]
  const void*  mask  = d_in[2];                 // [N, 32]
  const float* W1    = (const float*)d_in[3];   // [512, 512]
  const float* Wa    = (const float*)d_in[4];   // [512, 1024]
  float* out = (float*)d_out;
  const int N = in_sizes[0] / ND;               // 20000
  const int Mp = ((N + 127) / 128) * 128;       // 20096

  unsigned char* ws = (unsigned char*)d_ws;
  float*         x     = (float*)ws;                         // N*2048 B
  unsigned char* prevP = ws + (size_t)N * 2048;              // Mp*2048
  unsigned char* aggP  = prevP + (size_t)Mp * 2048;          // Mp*2048
  unsigned char* W1P   = aggP + (size_t)Mp * 2048;           // 512*2048
  unsigned char* WaP   = W1P + (size_t)512 * 2048;           // 512*4096
  int*           flag  = (int*)(WaP + (size_t)512 * 4096);

  hipMemsetAsync(flag, 0, sizeof(int), stream);
  detect_mask_kernel<<<64, 256, 0, stream>>>((const unsigned int*)mask,
                                             (N * NK) / 4, flag);

  // pre-encode panel images (single launch)
  convert_panels3<<<2048, 256, 0, stream>>>(prev, prevP, N, Mp, W1, W1P, Wa, WaP);

  const int nwg = (Mp / 128) * 4;  // 1-D grid, bn innermost, XCD-swizzled

  // x = prev @ W1^T  (split-3: score path needs full precision)
  gemm_mfma<false, false, true><<<nwg, 256, 0, stream>>>(prevP, nullptr, W1P, x, N, ND, 16);

  // scores -> softmax -> agg (unmasked neigh streamed once)
  attn_fused<<<N, 512, 0, stream>>>(neigh, x, mask, flag, aggP);

  // out = tanh(concat(agg, prev) @ Wa^T)  (split-2: tanh-output path)
  gemm_mfma<true, true, false><<<nwg, 256, 0, stream>>>(aggP, prevP, WaP, out, N, ND, 32);
}

// Round 10
// 325.150 us; speedup vs baseline: 1.3255x; 1.0847x over previous
//
#include <hip/hip_runtime.h>
#include <math.h>

#define ND 512
#define NK 32

typedef __attribute__((ext_vector_type(8))) short short8;
typedef __attribute__((ext_vector_type(4))) float f32x4;
typedef __attribute__((address_space(1))) const unsigned int glds_src;
typedef __attribute__((address_space(3))) unsigned int glds_dst;

__device__ inline unsigned short f2bf(float x) {
  unsigned u = __float_as_uint(x);
  unsigned r = (u + 0x7fffu + ((u >> 16) & 1u)) >> 16;  // RNE
  return (unsigned short)r;
}
__device__ inline float bf2f(unsigned short h) {
  return __uint_as_float(((unsigned)h) << 16);
}
__device__ inline void gload_lds16(const void* g, void* l) {
  __builtin_amdgcn_global_load_lds((glds_src*)g, (glds_dst*)l, 16, 0, 0);
}
__device__ inline float fast_tanh(float v) {
  const float c = fminf(fmaxf(v, -15.f), 15.f);
  const float e = __expf(2.f * c);
  return 1.f - 2.f / (e + 1.f);
}

// bijective XCD chunking (m204)
__device__ inline int xcd_swz(int orig, int nwg) {
  const int q = nwg >> 3, r = nwg & 7;
  const int xcd = orig & 7, pos = orig >> 3;
  return (xcd < r ? xcd * (q + 1) : r * (q + 1) + (xcd - r) * q) + pos;
}

// ---------------- panel converters ----------------
// INTERLEAVED (B-side: W1P/WaP): per k-block 128 B = 4 x [hi16|lo16],
//   hi at (s*32)^sw, lo at (s*32+16)^sw, sw=(row&7)<<4.
// PLANE (A-side: prevHi/prevLo/aggHi): per k-block 64 B = 4 x 16 B,
//   slot s stored at phys=(s^((row>>1)&3))*16 — swizzle baked into layout so
//   GEMM staging is a linear global_load_lds row copy; readers XOR at ds_read.
template<int KD>
__device__ inline void conv_int(const float* __restrict__ src,
                                unsigned char* __restrict__ dst,
                                int rows_src, long long c) {
  constexpr int CPR = KD * 4;
  const int r = (int)(c / CPR);      // constexpr pow2 -> shift
  const int rem = (int)(c % CPR);
  const int kb = rem >> 2;
  const int s = rem & 3;
  const int sw = (r & 7) << 4;
  unsigned short h[8], l[8];
  if (r < rows_src) {
    const float* p = src + (size_t)r * (KD * 32) + kb * 32 + s * 8;
    #pragma unroll
    for (int j = 0; j < 8; j++) {
      const float v = p[j];
      h[j] = f2bf(v);
      l[j] = f2bf(v - bf2f(h[j]));
    }
  } else {
    #pragma unroll
    for (int j = 0; j < 8; j++) { h[j] = 0; l[j] = 0; }
  }
  uint4 hv, lv;
  hv.x = (unsigned)h[0] | ((unsigned)h[1] << 16);
  hv.y = (unsigned)h[2] | ((unsigned)h[3] << 16);
  hv.z = (unsigned)h[4] | ((unsigned)h[5] << 16);
  hv.w = (unsigned)h[6] | ((unsigned)h[7] << 16);
  lv.x = (unsigned)l[0] | ((unsigned)l[1] << 16);
  lv.y = (unsigned)l[2] | ((unsigned)l[3] << 16);
  lv.z = (unsigned)l[4] | ((unsigned)l[5] << 16);
  lv.w = (unsigned)l[6] | ((unsigned)l[7] << 16);
  unsigned char* rowb = dst + (size_t)r * (KD * 128) + kb * 128;
  *(uint4*)(rowb + ((s * 32) ^ sw)) = hv;
  *(uint4*)(rowb + ((s * 32 + 16) ^ sw)) = lv;
}

__device__ inline void conv_plane(const float* __restrict__ src,
                                  unsigned char* __restrict__ dhi,
                                  unsigned char* __restrict__ dlo,
                                  int rows_src, long long c) {  // KD=16
  const int r = (int)(c >> 6);
  const int rem = (int)(c & 63);
  const int kb = rem >> 2;
  const int s = rem & 3;
  unsigned short h[8], l[8];
  if (r < rows_src) {
    const float* p = src + (size_t)r * 512 + kb * 32 + s * 8;
    #pragma unroll
    for (int j = 0; j < 8; j++) {
      const float v = p[j];
      h[j] = f2bf(v);
      l[j] = f2bf(v - bf2f(h[j]));
    }
  } else {
    #pragma unroll
    for (int j = 0; j < 8; j++) { h[j] = 0; l[j] = 0; }
  }
  uint4 hv, lv;
  hv.x = (unsigned)h[0] | ((unsigned)h[1] << 16);
  hv.y = (unsigned)h[2] | ((unsigned)h[3] << 16);
  hv.z = (unsigned)h[4] | ((unsigned)h[5] << 16);
  hv.w = (unsigned)h[6] | ((unsigned)h[7] << 16);
  lv.x = (unsigned)l[0] | ((unsigned)l[1] << 16);
  lv.y = (unsigned)l[2] | ((unsigned)l[3] << 16);
  lv.z = (unsigned)l[4] | ((unsigned)l[5] << 16);
  lv.w = (unsigned)l[6] | ((unsigned)l[7] << 16);
  const size_t off = (size_t)r * 1024 + kb * 64 + (((s ^ ((r >> 1) & 3))) << 4);
  *(uint4*)(dhi + off) = hv;
  *(uint4*)(dlo + off) = lv;
}

// one launch: mask-dtype detect + all panel encodes
__global__ void convert_all(const float* __restrict__ prev,
                            unsigned char* __restrict__ prevHi,
                            unsigned char* __restrict__ prevLo,
                            int Np, int Mp,
                            const float* __restrict__ W1, unsigned char* __restrict__ W1P,
                            const float* __restrict__ Wa, unsigned char* __restrict__ WaP,
                            const unsigned int* __restrict__ maskw, int nwords,
                            int* __restrict__ flag) {
  const long long gtid = (long long)blockIdx.x * blockDim.x + threadIdx.x;
  const long long gstride = (long long)gridDim.x * blockDim.x;

  int local = 0;
  for (long long i = gtid; i < nwords; i += gstride)
    if (maskw[i] > 1u) local = 1;
  if (__any(local)) {
    if ((threadIdx.x & 63) == 0) atomicOr(flag, 1);
  }

  const long long c0 = (long long)Mp * 64;          // prev plane chunks
  const long long c1 = c0 + 512 * 64;               // + W1 interleaved
  const long long c2 = c1 + 512 * 128;              // + Wa interleaved
  for (long long c = gtid; c < c2; c += gstride) {
    if (c < c0)      conv_plane(prev, prevHi, prevLo, Np, c);
    else if (c < c1) conv_int<16>(W1, W1P, 512, c - c0);
    else             conv_int<32>(Wa, WaP, 512, c - c1);
  }
}

// ---------------- gemm1: x = prev @ W1^T (split-3) ----------------
// A from planes (hi+lo, 8 KB each), B = W1P interleaved (16 KB). 32 KB LDS,
// 3 blocks/CU, single-buffered m97 structure (dbuf loses occupancy: R4/R8).
__global__ __launch_bounds__(256, 3) void gemm_x(
    const unsigned char* __restrict__ Ahi, const unsigned char* __restrict__ Alo,
    const unsigned char* __restrict__ B, float* __restrict__ C, int M)
{
  __shared__ unsigned char AhP[8192];
  __shared__ unsigned char AlP[8192];
  __shared__ unsigned char BsP[16384];
  const int tid = threadIdx.x;
  const int lane = tid & 63;
  const int wv = tid >> 6;
  const int wr = wv >> 1, wc = wv & 1;
  const int wgid = xcd_swz(blockIdx.x, gridDim.x);
  const int bm = (wgid >> 2) * 128, bn = (wgid & 3) * 128;

  f32x4 acc[4][4];
  #pragma unroll
  for (int i = 0; i < 4; i++)
    #pragma unroll
    for (int j = 0; j < 4; j++) acc[i][j] = (f32x4){0.f, 0.f, 0.f, 0.f};

  const int s16 = (lane >> 4) * 32;           // B interleaved slot byte
  const int q = lane >> 4;                    // A plane slot index
  const int arow = (wv << 4) + (lane >> 2);   // A staging row (+i*64)
  const int aslot = (lane & 3) * 16;
  const int lrow0 = (wv << 3) + (lane >> 3);  // B staging row (+i*32)
  const int lbyte = (lane & 7) * 16;

  for (int kb = 0; kb < 16; kb++) {
    #pragma unroll
    for (int i = 0; i < 2; i++) {
      const size_t asrc = (size_t)(bm + i * 64 + arow) * 1024 + kb * 64 + aslot;
      gload_lds16(Ahi + asrc, AhP + i * 4096 + wv * 1024);
      gload_lds16(Alo + asrc, AlP + i * 4096 + wv * 1024);
    }
    #pragma unroll
    for (int i = 0; i < 4; i++) {
      gload_lds16(B + (size_t)(bn + i * 32 + lrow0) * 2048 + kb * 128 + lbyte,
                  BsP + i * 4096 + wv * 1024);
    }
    __syncthreads();

    short8 bh[4], bl[4];
    #pragma unroll
    for (int fn = 0; fn < 4; fn++) {
      const int row = wc * 64 + fn * 16 + (lane & 15);
      const int sw = (row & 7) << 4;
      bh[fn] = *(const short8*)(BsP + row * 128 + (s16 ^ sw));
      bl[fn] = *(const short8*)(BsP + row * 128 + ((s16 + 16) ^ sw));
    }
    #pragma unroll
    for (int fm = 0; fm < 4; fm++) {
      const int row = wr * 64 + fm * 16 + (lane & 15);
      const int aoff = row * 64 + ((q ^ ((row >> 1) & 3)) << 4);
      const short8 ah = *(const short8*)(AhP + aoff);
      const short8 al = *(const short8*)(AlP + aoff);
      #pragma unroll
      for (int fn = 0; fn < 4; fn++) {
        acc[fm][fn] = __builtin_amdgcn_mfma_f32_16x16x32_bf16(ah, bh[fn], acc[fm][fn], 0, 0, 0);
        acc[fm][fn] = __builtin_amdgcn_mfma_f32_16x16x32_bf16(ah, bl[fn], acc[fm][fn], 0, 0, 0);
        acc[fm][fn] = __builtin_amdgcn_mfma_f32_16x16x32_bf16(al, bh[fn], acc[fm][fn], 0, 0, 0);
      }
    }
    __syncthreads();
  }

  #pragma unroll
  for (int fm = 0; fm < 4; fm++) {
    #pragma unroll
    for (int fn = 0; fn < 4; fn++) {
      const int col = bn + wc * 64 + fn * 16 + (lane & 15);
      #pragma unroll
      for (int j = 0; j < 4; j++) {
        const int row = bm + wr * 64 + fm * 16 + (lane >> 4) * 4 + j;
        if (row < M) C[(size_t)row * ND + col] = acc[fm][fn][j];
      }
    }
  }
}

// ---------------- gemm2: out = tanh([agg|prev] @ Wa^T) (split-2) --------
// A hi-plane only (8 KB; lo never read by split-2 -> 41 MB fetch saved),
// B = WaP interleaved (16 KB). 24 KB LDS.
__global__ __launch_bounds__(256, 3) void gemm_out(
    const unsigned char* __restrict__ Agg, const unsigned char* __restrict__ Aprev,
    const unsigned char* __restrict__ B, float* __restrict__ C, int M)
{
  __shared__ unsigned char AhP[8192];
  __shared__ unsigned char BsP[16384];
  const int tid = threadIdx.x;
  const int lane = tid & 63;
  const int wv = tid >> 6;
  const int wr = wv >> 1, wc = wv & 1;
  const int wgid = xcd_swz(blockIdx.x, gridDim.x);
  const int bm = (wgid >> 2) * 128, bn = (wgid & 3) * 128;

  f32x4 acc[4][4];
  #pragma unroll
  for (int i = 0; i < 4; i++)
    #pragma unroll
    for (int j = 0; j < 4; j++) acc[i][j] = (f32x4){0.f, 0.f, 0.f, 0.f};

  const int s16 = (lane >> 4) * 32;
  const int q = lane >> 4;
  const int arow = (wv << 4) + (lane >> 2);
  const int aslot = (lane & 3) * 16;
  const int lrow0 = (wv << 3) + (lane >> 3);
  const int lbyte = (lane & 7) * 16;

  for (int kb = 0; kb < 32; kb++) {
    const unsigned char* Ap = (kb < 16) ? Agg : Aprev;
    const int akb = kb & 15;
    #pragma unroll
    for (int i = 0; i < 2; i++) {
      gload_lds16(Ap + (size_t)(bm + i * 64 + arow) * 1024 + akb * 64 + aslot,
                  AhP + i * 4096 + wv * 1024);
    }
    #pragma unroll
    for (int i = 0; i < 4; i++) {
      gload_lds16(B + (size_t)(bn + i * 32 + lrow0) * 4096 + kb * 128 + lbyte,
                  BsP + i * 4096 + wv * 1024);
    }
    __syncthreads();

    short8 bh[4], bl[4];
    #pragma unroll
    for (int fn = 0; fn < 4; fn++) {
      const int row = wc * 64 + fn * 16 + (lane & 15);
      const int sw = (row & 7) << 4;
      bh[fn] = *(const short8*)(BsP + row * 128 + (s16 ^ sw));
      bl[fn] = *(const short8*)(BsP + row * 128 + ((s16 + 16) ^ sw));
    }
    #pragma unroll
    for (int fm = 0; fm < 4; fm++) {
      const int row = wr * 64 + fm * 16 + (lane & 15);
      const int aoff = row * 64 + ((q ^ ((row >> 1) & 3)) << 4);
      const short8 ah = *(const short8*)(AhP + aoff);
      #pragma unroll
      for (int fn = 0; fn < 4; fn++) {
        acc[fm][fn] = __builtin_amdgcn_mfma_f32_16x16x32_bf16(ah, bh[fn], acc[fm][fn], 0, 0, 0);
        acc[fm][fn] = __builtin_amdgcn_mfma_f32_16x16x32_bf16(ah, bl[fn], acc[fm][fn], 0, 0, 0);
      }
    }
    __syncthreads();
  }

  #pragma unroll
  for (int fm = 0; fm < 4; fm++) {
    #pragma unroll
    for (int fn = 0; fn < 4; fn++) {
      const int col = bn + wc * 64 + fn * 16 + (lane & 15);
      #pragma unroll
      for (int j = 0; j < 4; j++) {
        const int row = bm + wr * 64 + fm * 16 + (lane >> 4) * 4 + j;
        if (row < M) C[(size_t)row * ND + col] = fast_tanh(acc[fm][fn][j]);
      }
    }
  }
}

// ---------------- fused scores + softmax + aggregate ----------------
// One block (512 thr / 8 waves) per row; UNMASKED neighbors streamed once
// (wave-uniform skip). agg emitted as HI plane only (lo is dead in split-2).
__global__ __launch_bounds__(512) void attn_fused(
    const float* __restrict__ neigh,   // [N, 32, 512]
    const float* __restrict__ x,       // [N, 512] f32
    const void* __restrict__ mask,     // [N, 32] int32 or u8 (see flag)
    const int* __restrict__ mask_is_u8,
    unsigned char* __restrict__ aggHi) // hi plane, 1024 B/row
{
  __shared__ float part[8][ND];
  __shared__ float sc_s[NK];
  __shared__ float attn_s[NK];
  __shared__ unsigned char img[1024];
  const int n = blockIdx.x;
  const int tid = threadIdx.x;
  const int wv = tid >> 6;
  const int lane = tid & 63;

  // wave-uniform mask for this wave's 4 neighbors (same-addr load = broadcast)
  const int u8m = *mask_is_u8;
  int mk[4];
  #pragma unroll
  for (int j = 0; j < 4; j++) {
    mk[j] = u8m ? (int)((const unsigned char*)mask)[(size_t)n * NK + wv * 4 + j]
                : ((const int*)mask)[(size_t)n * NK + wv * 4 + j];
  }

  const float4 xa = *(const float4*)(x + (size_t)n * ND + lane * 4);
  const float4 xb = *(const float4*)(x + (size_t)n * ND + 256 + lane * 4);

  const float4* nbase = (const float4*)(neigh + ((size_t)n * NK + wv * 4) * ND);
  float4 na[4], nb[4];

  #pragma unroll
  for (int j = 0; j < 4; j++) {
    if (!mk[j]) {
      na[j] = nbase[j * 128 + lane];
      nb[j] = nbase[j * 128 + 64 + lane];
      float p = na[j].x * xa.x + na[j].y * xa.y + na[j].z * xa.z + na[j].w * xa.w
              + nb[j].x * xb.x + nb[j].y * xb.y + nb[j].z * xb.z + nb[j].w * xb.w;
      #pragma unroll
      for (int off = 32; off; off >>= 1) p += __shfl_xor(p, off);
      if (lane == 0) sc_s[wv * 4 + j] = p;
    }
  }
  __syncthreads();

  if (tid < NK) {
    const int mks = u8m
        ? (int)((const unsigned char*)mask)[(size_t)n * NK + tid]
        : ((const int*)mask)[(size_t)n * NK + tid];
    float s = mks ? -3.4e38f : sc_s[tid];
    float m = s;
    #pragma unroll
    for (int off = 16; off; off >>= 1) m = fmaxf(m, __shfl_xor(m, off, 32));
    const float p = mks ? 0.f : expf(s - m);
    float t = p;
    #pragma unroll
    for (int off = 16; off; off >>= 1) t += __shfl_xor(t, off, 32);
    attn_s[tid] = p / t;
  }
  __syncthreads();

  float4 acc0 = make_float4(0.f, 0.f, 0.f, 0.f);
  float4 acc1 = make_float4(0.f, 0.f, 0.f, 0.f);
  #pragma unroll
  for (int j = 0; j < 4; j++) {
    if (!mk[j]) {
      const float w = attn_s[wv * 4 + j];
      acc0.x = fmaf(w, na[j].x, acc0.x);
      acc0.y = fmaf(w, na[j].y, acc0.y);
      acc0.z = fmaf(w, na[j].z, acc0.z);
      acc0.w = fmaf(w, na[j].w, acc0.w);
      acc1.x = fmaf(w, nb[j].x, acc1.x);
      acc1.y = fmaf(w, nb[j].y, acc1.y);
      acc1.z = fmaf(w, nb[j].z, acc1.z);
      acc1.w = fmaf(w, nb[j].w, acc1.w);
    }
  }
  *(float4*)&part[wv][lane * 4] = acc0;
  *(float4*)&part[wv][256 + lane * 4] = acc1;
  __syncthreads();
  float ssum = 0.f;
  #pragma unroll
  for (int w = 0; w < 8; w++) ssum += part[w][tid];

  // hi-plane encode: k = tid -> kb, slot s, elem j; phys slot = s ^ ((n>>1)&3)
  {
    const int g = (n >> 1) & 3;
    const int kb = tid >> 5;
    const int s = (tid >> 3) & 3;
    const int j = tid & 7;
    *(unsigned short*)(img + kb * 64 + ((s ^ g) << 4) + j * 2) = f2bf(ssum);
  }
  __syncthreads();
  if (tid < 64) {
    *(uint4*)(aggHi + (size_t)n * 1024 + tid * 16) = *(const uint4*)(img + tid * 16);
  }
}

extern "C" void kernel_launch(void* const* d_in, const int* in_sizes, int n_in,
                              void* d_out, int out_size, void* d_ws, size_t ws_size,
                              hipStream_t stream) {
  const float* prev  = (const float*)d_in[0];   // [N, 512]
  const float* neigh = (const float*)d_in[1];   // [N, 32, 512]
  const void*  mask  = d_in[2];                 // [N, 32]
  const float* W1    = (const float*)d_in[3];   // [512, 512]
  const float* Wa    = (const float*)d_in[4];   // [512, 1024]
  float* out = (float*)d_out;
  const int N = in_sizes[0] / ND;               // 20000
  const int Mp = ((N + 127) / 128) * 128;       // 20096

  unsigned char* ws = (unsigned char*)d_ws;
  float*         x      = (float*)ws;                         // N*2048 B
  unsigned char* prevHi = ws + (size_t)N * 2048;              // Mp*1024
  unsigned char* prevLo = prevHi + (size_t)Mp * 1024;         // Mp*1024
  unsigned char* aggHi  = prevLo + (size_t)Mp * 1024;         // Mp*1024
  unsigned char* W1P    = aggHi + (size_t)Mp * 1024;          // 512*2048
  unsigned char* WaP    = W1P + (size_t)512 * 2048;           // 512*4096
  int*           flag   = (int*)(WaP + (size_t)512 * 4096);

  hipMemsetAsync(flag, 0, sizeof(int), stream);

  // detect + all panel encodes, one launch
  convert_all<<<2048, 256, 0, stream>>>(prev, prevHi, prevLo, N, Mp,
                                        W1, W1P, Wa, WaP,
                                        (const unsigned int*)mask, (N * NK) / 4, flag);

  const int nwg = (Mp / 128) * 4;  // 1-D grid, bn innermost, XCD-swizzled

  // x = prev @ W1^T  (split-3: score path needs full precision)
  gemm_x<<<nwg, 256, 0, stream>>>(prevHi, prevLo, W1P, x, N);

  // scores -> softmax -> agg (unmasked neigh streamed once; hi plane out)
  attn_fused<<<N, 512, 0, stream>>>(neigh, x, mask, flag, aggHi);

  // out = tanh(concat(agg, prev) @ Wa^T)  (split-2: A hi plane only)
  gemm_out<<<nwg, 256, 0, stream>>>(aggHi, prevHi, WaP, out, N);
}

// Round 11
// 324.980 us; speedup vs baseline: 1.3262x; 1.0005x over previous
//
#include <hip/hip_runtime.h>
#include <math.h>

#define ND 512
#define NK 32

typedef __attribute__((ext_vector_type(8))) short short8;
typedef __attribute__((ext_vector_type(4))) float f32x4;
typedef __attribute__((address_space(1))) const unsigned int glds_src;
typedef __attribute__((address_space(3))) unsigned int glds_dst;

__device__ inline unsigned short f2bf(float x) {
  unsigned u = __float_as_uint(x);
  unsigned r = (u + 0x7fffu + ((u >> 16) & 1u)) >> 16;  // RNE
  return (unsigned short)r;
}
__device__ inline float bf2f(unsigned short h) {
  return __uint_as_float(((unsigned)h) << 16);
}
__device__ inline void gload_lds16(const void* g, void* l) {
  __builtin_amdgcn_global_load_lds((glds_src*)g, (glds_dst*)l, 16, 0, 0);
}
__device__ inline float fast_tanh(float v) {
  const float c = fminf(fmaxf(v, -15.f), 15.f);
  const float e = __expf(2.f * c);
  return 1.f - 2.f / (e + 1.f);
}

// bijective XCD chunking (m204)
__device__ inline int xcd_swz(int orig, int nwg) {
  const int q = nwg >> 3, r = nwg & 7;
  const int xcd = orig & 7, pos = orig >> 3;
  return (xcd < r ? xcd * (q + 1) : r * (q + 1) + (xcd - r) * q) + pos;
}

// ---------------- panel converters ----------------
// INTERLEAVED (B-side: W1P/WaP): per k-block 128 B = 4 x [hi16|lo16],
//   hi at (s*32)^sw, lo at (s*32+16)^sw, sw=(row&7)<<4.
// PLANE (A-side: prevHi/prevLo/aggHi): per k-block 64 B = 4 x 16 B,
//   slot s stored at phys=(s^((row>>1)&3))*16 — swizzle baked into layout so
//   GEMM staging is a linear global_load_lds row copy; readers XOR at ds_read.
template<int KD>
__device__ inline void conv_int(const float* __restrict__ src,
                                unsigned char* __restrict__ dst,
                                int rows_src, long long c) {
  constexpr int CPR = KD * 4;
  const int r = (int)(c / CPR);      // constexpr pow2 -> shift
  const int rem = (int)(c % CPR);
  const int kb = rem >> 2;
  const int s = rem & 3;
  const int sw = (r & 7) << 4;
  unsigned short h[8], l[8];
  if (r < rows_src) {
    const float* p = src + (size_t)r * (KD * 32) + kb * 32 + s * 8;
    #pragma unroll
    for (int j = 0; j < 8; j++) {
      const float v = p[j];
      h[j] = f2bf(v);
      l[j] = f2bf(v - bf2f(h[j]));
    }
  } else {
    #pragma unroll
    for (int j = 0; j < 8; j++) { h[j] = 0; l[j] = 0; }
  }
  uint4 hv, lv;
  hv.x = (unsigned)h[0] | ((unsigned)h[1] << 16);
  hv.y = (unsigned)h[2] | ((unsigned)h[3] << 16);
  hv.z = (unsigned)h[4] | ((unsigned)h[5] << 16);
  hv.w = (unsigned)h[6] | ((unsigned)h[7] << 16);
  lv.x = (unsigned)l[0] | ((unsigned)l[1] << 16);
  lv.y = (unsigned)l[2] | ((unsigned)l[3] << 16);
  lv.z = (unsigned)l[4] | ((unsigned)l[5] << 16);
  lv.w = (unsigned)l[6] | ((unsigned)l[7] << 16);
  unsigned char* rowb = dst + (size_t)r * (KD * 128) + kb * 128;
  *(uint4*)(rowb + ((s * 32) ^ sw)) = hv;
  *(uint4*)(rowb + ((s * 32 + 16) ^ sw)) = lv;
}

__device__ inline void conv_plane(const float* __restrict__ src,
                                  unsigned char* __restrict__ dhi,
                                  unsigned char* __restrict__ dlo,
                                  int rows_src, long long c) {  // KD=16
  const int r = (int)(c >> 6);
  const int rem = (int)(c & 63);
  const int kb = rem >> 2;
  const int s = rem & 3;
  unsigned short h[8], l[8];
  if (r < rows_src) {
    const float* p = src + (size_t)r * 512 + kb * 32 + s * 8;
    #pragma unroll
    for (int j = 0; j < 8; j++) {
      const float v = p[j];
      h[j] = f2bf(v);
      l[j] = f2bf(v - bf2f(h[j]));
    }
  } else {
    #pragma unroll
    for (int j = 0; j < 8; j++) { h[j] = 0; l[j] = 0; }
  }
  uint4 hv, lv;
  hv.x = (unsigned)h[0] | ((unsigned)h[1] << 16);
  hv.y = (unsigned)h[2] | ((unsigned)h[3] << 16);
  hv.z = (unsigned)h[4] | ((unsigned)h[5] << 16);
  hv.w = (unsigned)h[6] | ((unsigned)h[7] << 16);
  lv.x = (unsigned)l[0] | ((unsigned)l[1] << 16);
  lv.y = (unsigned)l[2] | ((unsigned)l[3] << 16);
  lv.z = (unsigned)l[4] | ((unsigned)l[5] << 16);
  lv.w = (unsigned)l[6] | ((unsigned)l[7] << 16);
  const size_t off = (size_t)r * 1024 + kb * 64 + (((s ^ ((r >> 1) & 3))) << 4);
  *(uint4*)(dhi + off) = hv;
  *(uint4*)(dlo + off) = lv;
}

// one launch: mask-dtype detect + all panel encodes
__global__ void convert_all(const float* __restrict__ prev,
                            unsigned char* __restrict__ prevHi,
                            unsigned char* __restrict__ prevLo,
                            int Np, int Mp,
                            const float* __restrict__ W1, unsigned char* __restrict__ W1P,
                            const float* __restrict__ Wa, unsigned char* __restrict__ WaP,
                            const unsigned int* __restrict__ maskw, int nwords,
                            int* __restrict__ flag) {
  const long long gtid = (long long)blockIdx.x * blockDim.x + threadIdx.x;
  const long long gstride = (long long)gridDim.x * blockDim.x;

  int local = 0;
  for (long long i = gtid; i < nwords; i += gstride)
    if (maskw[i] > 1u) local = 1;
  if (__any(local)) {
    if ((threadIdx.x & 63) == 0) atomicOr(flag, 1);
  }

  const long long c0 = (long long)Mp * 64;          // prev plane chunks
  const long long c1 = c0 + 512 * 64;               // + W1 interleaved
  const long long c2 = c1 + 512 * 128;              // + Wa interleaved
  for (long long c = gtid; c < c2; c += gstride) {
    if (c < c0)      conv_plane(prev, prevHi, prevLo, Np, c);
    else if (c < c1) conv_int<16>(W1, W1P, 512, c - c0);
    else             conv_int<32>(Wa, WaP, 512, c - c1);
  }
}

// ---------------- gemm1: x = prev @ W1^T (split-3) ----------------
// A from planes (hi+lo, 8 KB each), B = W1P interleaved (16 KB). 32 KB LDS,
// 3 blocks/CU, single-buffered m97 structure (dbuf loses occupancy: R4/R8).
__global__ __launch_bounds__(256, 3) void gemm_x(
    const unsigned char* __restrict__ Ahi, const unsigned char* __restrict__ Alo,
    const unsigned char* __restrict__ B, float* __restrict__ C, int M)
{
  __shared__ unsigned char AhP[8192];
  __shared__ unsigned char AlP[8192];
  __shared__ unsigned char BsP[16384];
  const int tid = threadIdx.x;
  const int lane = tid & 63;
  const int wv = tid >> 6;
  const int wr = wv >> 1, wc = wv & 1;
  const int wgid = xcd_swz(blockIdx.x, gridDim.x);
  const int bm = (wgid >> 2) * 128, bn = (wgid & 3) * 128;

  f32x4 acc[4][4];
  #pragma unroll
  for (int i = 0; i < 4; i++)
    #pragma unroll
    for (int j = 0; j < 4; j++) acc[i][j] = (f32x4){0.f, 0.f, 0.f, 0.f};

  const int s16 = (lane >> 4) * 32;           // B interleaved slot byte
  const int q = lane >> 4;                    // A plane slot index
  const int arow = (wv << 4) + (lane >> 2);   // A staging row (+i*64)
  const int aslot = (lane & 3) * 16;
  const int lrow0 = (wv << 3) + (lane >> 3);  // B staging row (+i*32)
  const int lbyte = (lane & 7) * 16;

  for (int kb = 0; kb < 16; kb++) {
    #pragma unroll
    for (int i = 0; i < 2; i++) {
      const size_t asrc = (size_t)(bm + i * 64 + arow) * 1024 + kb * 64 + aslot;
      gload_lds16(Ahi + asrc, AhP + i * 4096 + wv * 1024);
      gload_lds16(Alo + asrc, AlP + i * 4096 + wv * 1024);
    }
    #pragma unroll
    for (int i = 0; i < 4; i++) {
      gload_lds16(B + (size_t)(bn + i * 32 + lrow0) * 2048 + kb * 128 + lbyte,
                  BsP + i * 4096 + wv * 1024);
    }
    __syncthreads();

    short8 bh[4], bl[4];
    #pragma unroll
    for (int fn = 0; fn < 4; fn++) {
      const int row = wc * 64 + fn * 16 + (lane & 15);
      const int sw = (row & 7) << 4;
      bh[fn] = *(const short8*)(BsP + row * 128 + (s16 ^ sw));
      bl[fn] = *(const short8*)(BsP + row * 128 + ((s16 + 16) ^ sw));
    }
    #pragma unroll
    for (int fm = 0; fm < 4; fm++) {
      const int row = wr * 64 + fm * 16 + (lane & 15);
      const int aoff = row * 64 + ((q ^ ((row >> 1) & 3)) << 4);
      const short8 ah = *(const short8*)(AhP + aoff);
      const short8 al = *(const short8*)(AlP + aoff);
      #pragma unroll
      for (int fn = 0; fn < 4; fn++) {
        acc[fm][fn] = __builtin_amdgcn_mfma_f32_16x16x32_bf16(ah, bh[fn], acc[fm][fn], 0, 0, 0);
        acc[fm][fn] = __builtin_amdgcn_mfma_f32_16x16x32_bf16(ah, bl[fn], acc[fm][fn], 0, 0, 0);
        acc[fm][fn] = __builtin_amdgcn_mfma_f32_16x16x32_bf16(al, bh[fn], acc[fm][fn], 0, 0, 0);
      }
    }
    __syncthreads();
  }

  #pragma unroll
  for (int fm = 0; fm < 4; fm++) {
    #pragma unroll
    for (int fn = 0; fn < 4; fn++) {
      const int col = bn + wc * 64 + fn * 16 + (lane & 15);
      #pragma unroll
      for (int j = 0; j < 4; j++) {
        const int row = bm + wr * 64 + fm * 16 + (lane >> 4) * 4 + j;
        if (row < M) C[(size_t)row * ND + col] = acc[fm][fn][j];
      }
    }
  }
}

// ---------------- gemm2: out = tanh([agg|prev] @ Wa^T) (split-2) --------
// MERGED K-step: one barrier window stages TWO k-blocks (Agg[kb] -> half 0,
// prevHi[kb] -> half 1, Wa k-blocks kb and kb+16) = 64 MFMA / 12 gloads per
// window, 16 windows instead of 32 -> per-MFMA barrier cost halved.
// LDS 2*8 + 2*16 = 48 KB -> still 3 blocks/CU (the R4/R8 trap avoided).
__global__ __launch_bounds__(256, 3) void gemm_out(
    const unsigned char* __restrict__ Agg, const unsigned char* __restrict__ Aprev,
    const unsigned char* __restrict__ B, float* __restrict__ C, int M)
{
  __shared__ unsigned char AhP[2][8192];
  __shared__ unsigned char BsP[2][16384];
  const int tid = threadIdx.x;
  const int lane = tid & 63;
  const int wv = tid >> 6;
  const int wr = wv >> 1, wc = wv & 1;
  const int wgid = xcd_swz(blockIdx.x, gridDim.x);
  const int bm = (wgid >> 2) * 128, bn = (wgid & 3) * 128;

  f32x4 acc[4][4];
  #pragma unroll
  for (int i = 0; i < 4; i++)
    #pragma unroll
    for (int j = 0; j < 4; j++) acc[i][j] = (f32x4){0.f, 0.f, 0.f, 0.f};

  const int s16 = (lane >> 4) * 32;
  const int q = lane >> 4;
  const int arow = (wv << 4) + (lane >> 2);
  const int aslot = (lane & 3) * 16;
  const int lrow0 = (wv << 3) + (lane >> 3);
  const int lbyte = (lane & 7) * 16;

  for (int kb = 0; kb < 16; kb++) {
    // half 0: Agg k-block kb (K 0..511); half 1: prevHi k-block kb (K 512..1023)
    #pragma unroll
    for (int i = 0; i < 2; i++) {
      const size_t arow_off = (size_t)(bm + i * 64 + arow) * 1024 + kb * 64 + aslot;
      gload_lds16(Agg + arow_off, AhP[0] + i * 4096 + wv * 1024);
      gload_lds16(Aprev + arow_off, AhP[1] + i * 4096 + wv * 1024);
    }
    #pragma unroll
    for (int i = 0; i < 4; i++) {
      const size_t brow = (size_t)(bn + i * 32 + lrow0) * 4096;
      gload_lds16(B + brow + kb * 128 + lbyte, BsP[0] + i * 4096 + wv * 1024);
      gload_lds16(B + brow + (kb + 16) * 128 + lbyte, BsP[1] + i * 4096 + wv * 1024);
    }
    __syncthreads();

    #pragma unroll
    for (int h = 0; h < 2; h++) {
      short8 bh[4], bl[4];
      #pragma unroll
      for (int fn = 0; fn < 4; fn++) {
        const int row = wc * 64 + fn * 16 + (lane & 15);
        const int sw = (row & 7) << 4;
        bh[fn] = *(const short8*)(BsP[h] + row * 128 + (s16 ^ sw));
        bl[fn] = *(const short8*)(BsP[h] + row * 128 + ((s16 + 16) ^ sw));
      }
      #pragma unroll
      for (int fm = 0; fm < 4; fm++) {
        const int row = wr * 64 + fm * 16 + (lane & 15);
        const int aoff = row * 64 + ((q ^ ((row >> 1) & 3)) << 4);
        const short8 ah = *(const short8*)(AhP[h] + aoff);
        #pragma unroll
        for (int fn = 0; fn < 4; fn++) {
          acc[fm][fn] = __builtin_amdgcn_mfma_f32_16x16x32_bf16(ah, bh[fn], acc[fm][fn], 0, 0, 0);
          acc[fm][fn] = __builtin_amdgcn_mfma_f32_16x16x32_bf16(ah, bl[fn], acc[fm][fn], 0, 0, 0);
        }
      }
    }
    __syncthreads();
  }

  #pragma unroll
  for (int fm = 0; fm < 4; fm++) {
    #pragma unroll
    for (int fn = 0; fn < 4; fn++) {
      const int col = bn + wc * 64 + fn * 16 + (lane & 15);
      #pragma unroll
      for (int j = 0; j < 4; j++) {
        const int row = bm + wr * 64 + fm * 16 + (lane >> 4) * 4 + j;
        if (row < M) C[(size_t)row * ND + col] = fast_tanh(acc[fm][fn][j]);
      }
    }
  }
}

// ---------------- fused scores + softmax + aggregate ----------------
// One block (512 thr / 8 waves) per row; UNMASKED neighbors streamed once
// (wave-uniform skip). agg emitted as HI plane only (lo is dead in split-2).
__global__ __launch_bounds__(512) void attn_fused(
    const float* __restrict__ neigh,   // [N, 32, 512]
    const float* __restrict__ x,       // [N, 512] f32
    const void* __restrict__ mask,     // [N, 32] int32 or u8 (see flag)
    const int* __restrict__ mask_is_u8,
    unsigned char* __restrict__ aggHi) // hi plane, 1024 B/row
{
  __shared__ float part[8][ND];
  __shared__ float sc_s[NK];
  __shared__ float attn_s[NK];
  __shared__ unsigned char img[1024];
  const int n = blockIdx.x;
  const int tid = threadIdx.x;
  const int wv = tid >> 6;
  const int lane = tid & 63;

  // wave-uniform mask for this wave's 4 neighbors (same-addr load = broadcast)
  const int u8m = *mask_is_u8;
  int mk[4];
  #pragma unroll
  for (int j = 0; j < 4; j++) {
    mk[j] = u8m ? (int)((const unsigned char*)mask)[(size_t)n * NK + wv * 4 + j]
                : ((const int*)mask)[(size_t)n * NK + wv * 4 + j];
  }

  const float4 xa = *(const float4*)(x + (size_t)n * ND + lane * 4);
  const float4 xb = *(const float4*)(x + (size_t)n * ND + 256 + lane * 4);

  const float4* nbase = (const float4*)(neigh + ((size_t)n * NK + wv * 4) * ND);
  float4 na[4], nb[4];

  #pragma unroll
  for (int j = 0; j < 4; j++) {
    if (!mk[j]) {
      na[j] = nbase[j * 128 + lane];
      nb[j] = nbase[j * 128 + 64 + lane];
      float p = na[j].x * xa.x + na[j].y * xa.y + na[j].z * xa.z + na[j].w * xa.w
              + nb[j].x * xb.x + nb[j].y * xb.y + nb[j].z * xb.z + nb[j].w * xb.w;
      #pragma unroll
      for (int off = 32; off; off >>= 1) p += __shfl_xor(p, off);
      if (lane == 0) sc_s[wv * 4 + j] = p;
    }
  }
  __syncthreads();

  if (tid < NK) {
    const int mks = u8m
        ? (int)((const unsigned char*)mask)[(size_t)n * NK + tid]
        : ((const int*)mask)[(size_t)n * NK + tid];
    float s = mks ? -3.4e38f : sc_s[tid];
    float m = s;
    #pragma unroll
    for (int off = 16; off; off >>= 1) m = fmaxf(m, __shfl_xor(m, off, 32));
    const float p = mks ? 0.f : expf(s - m);
    float t = p;
    #pragma unroll
    for (int off = 16; off; off >>= 1) t += __shfl_xor(t, off, 32);
    attn_s[tid] = p / t;
  }
  __syncthreads();

  float4 acc0 = make_float4(0.f, 0.f, 0.f, 0.f);
  float4 acc1 = make_float4(0.f, 0.f, 0.f, 0.f);
  #pragma unroll
  for (int j = 0; j < 4; j++) {
    if (!mk[j]) {
      const float w = attn_s[wv * 4 + j];
      acc0.x = fmaf(w, na[j].x, acc0.x);
      acc0.y = fmaf(w, na[j].y, acc0.y);
      acc0.z = fmaf(w, na[j].z, acc0.z);
      acc0.w = fmaf(w, na[j].w, acc0.w);
      acc1.x = fmaf(w, nb[j].x, acc1.x);
      acc1.y = fmaf(w, nb[j].y, acc1.y);
      acc1.z = fmaf(w, nb[j].z, acc1.z);
      acc1.w = fmaf(w, nb[j].w, acc1.w);
    }
  }
  *(float4*)&part[wv][lane * 4] = acc0;
  *(float4*)&part[wv][256 + lane * 4] = acc1;
  __syncthreads();
  float ssum = 0.f;
  #pragma unroll
  for (int w = 0; w < 8; w++) ssum += part[w][tid];

  // hi-plane encode: k = tid -> kb, slot s, elem j; phys slot = s ^ ((n>>1)&3)
  {
    const int g = (n >> 1) & 3;
    const int kb = tid >> 5;
    const int s = (tid >> 3) & 3;
    const int j = tid & 7;
    *(unsigned short*)(img + kb * 64 + ((s ^ g) << 4) + j * 2) = f2bf(ssum);
  }
  __syncthreads();
  if (tid < 64) {
    *(uint4*)(aggHi + (size_t)n * 1024 + tid * 16) = *(const uint4*)(img + tid * 16);
  }
}

extern "C" void kernel_launch(void* const* d_in, const int* in_sizes, int n_in,
                              void* d_out, int out_size, void* d_ws, size_t ws_size,
                              hipStream_t stream) {
  const float* prev  = (const float*)d_in[0];   // [N, 512]
  const float* neigh = (const float*)d_in[1];   // [N, 32, 512]
  const void*  mask  = d_in[2];                 // [N, 32]
  const float* W1    = (const float*)d_in[3];   // [512, 512]
  const float* Wa    = (const float*)d_in[4];   // [512, 1024]
  float* out = (float*)d_out;
  const int N = in_sizes[0] / ND;               // 20000
  const int Mp = ((N + 127) / 128) * 128;       // 20096

  unsigned char* ws = (unsigned char*)d_ws;
  float*         x      = (float*)ws;                         // N*2048 B
  unsigned char* prevHi = ws + (size_t)N * 2048;              // Mp*1024
  unsigned char* prevLo = prevHi + (size_t)Mp * 1024;         // Mp*1024
  unsigned char* aggHi  = prevLo + (size_t)Mp * 1024;         // Mp*1024
  unsigned char* W1P    = aggHi + (size_t)Mp * 1024;          // 512*2048
  unsigned char* WaP    = W1P + (size_t)512 * 2048;           // 512*4096
  int*           flag   = (int*)(WaP + (size_t)512 * 4096);

  hipMemsetAsync(flag, 0, sizeof(int), stream);

  // detect + all panel encodes, one launch
  convert_all<<<2048, 256, 0, stream>>>(prev, prevHi, prevLo, N, Mp,
                                        W1, W1P, Wa, WaP,
                                        (const unsigned int*)mask, (N * NK) / 4, flag);

  const int nwg = (Mp / 128) * 4;  // 1-D grid, bn innermost, XCD-swizzled

  // x = prev @ W1^T  (split-3: score path needs full precision)
  gemm_x<<<nwg, 256, 0, stream>>>(prevHi, prevLo, W1P, x, N);

  // scores -> softmax -> agg (unmasked neigh streamed once; hi plane out)
  attn_fused<<<N, 512, 0, stream>>>(neigh, x, mask, flag, aggHi);

  // out = tanh(concat(agg, prev) @ Wa^T)  (split-2: A hi plane, merged k-step)
  gemm_out<<<nwg, 256, 0, stream>>>(aggHi, prevHi, WaP, out, N);
}